// Round 3
// baseline (13156.744 us; speedup 1.0000x reference)
//
#include <hip/hip_runtime.h>

#define WGSZ 1024
#define NWG  64

namespace {
constexpr int kN = 2048, kH = 256, kOO = 4096, kGW = 512;
// Transposed-weight workspace offsets (floats)
constexpr size_t OFF_ELA2 = 0;          // 4x256x256   -> R=1024 K4=64
constexpr size_t OFF_ELM1 = 262144;     // 4x256x4096  -> R=1024 K4=1024
constexpr size_t OFF_ELM2 = 4456448;    // 4x256x256
constexpr size_t OFF_EBL1 = 4718592;    // 4x256x512   -> R=1024 K4=128
constexpr size_t OFF_EBL2 = 5242880;
constexpr size_t OFF_DM1  = 5505024;
constexpr size_t OFF_DV1  = 5767168;
constexpr size_t OFF_WIH  = 6029312;    // 4x2x1024x256 -> R=8192 K4=64
constexpr size_t OFF_WHH  = 8126464;
constexpr size_t WS_FLOATS = 10223616;  // ~39 MB
}

// np.argmin(|centers - v|), first index on tie; centers in exact np fp32 order.
__device__ __forceinline__ int bin_idx(float v) {
  float t = fmaf(v, 5.0f, 63.5f);
  int i0 = (int)floorf(t);
  int c0 = i0 - 1; c0 = c0 < 0 ? 0 : (c0 > 127 ? 127 : c0);
  int c1 = i0;     c1 = c1 < 0 ? 0 : (c1 > 127 ? 127 : c1);
  int c2 = i0 + 1; c2 = c2 < 0 ? 0 : (c2 > 127 ? 127 : c2);
  float d0 = fabsf(__fmul_rn(__fadd_rn((float)(c0 - 64), 0.5f), 0.2f) - v);
  float d1 = fabsf(__fmul_rn(__fadd_rn((float)(c1 - 64), 0.5f), 0.2f) - v);
  float d2 = fabsf(__fmul_rn(__fadd_rn((float)(c2 - 64), 0.5f), 0.2f) - v);
  int best = c0; float bd = d0;
  if (d1 < bd) { bd = d1; best = c1; }
  if (d2 < bd) { bd = d2; best = c2; }
  return best;
}

// numpy pairwise_sum, exact replication for n=128 (LayerNorm only).
__device__ __forceinline__ float np_pw128(const float* a) {
  float r0=a[0],r1=a[1],r2=a[2],r3=a[3],r4=a[4],r5=a[5],r6=a[6],r7=a[7];
  for (int i = 8; i < 128; i += 8) {
    r0=__fadd_rn(r0,a[i+0]); r1=__fadd_rn(r1,a[i+1]);
    r2=__fadd_rn(r2,a[i+2]); r3=__fadd_rn(r3,a[i+3]);
    r4=__fadd_rn(r4,a[i+4]); r5=__fadd_rn(r5,a[i+5]);
    r6=__fadd_rn(r6,a[i+6]); r7=__fadd_rn(r7,a[i+7]);
  }
  return __fadd_rn(__fadd_rn(__fadd_rn(r0,r1),__fadd_rn(r2,r3)),
                   __fadd_rn(__fadd_rn(r4,r5),__fadd_rn(r6,r7)));
}
__device__ __forceinline__ float np_sum256(const float* a) {
  return __fadd_rn(np_pw128(a), np_pw128(a + 128));
}

__device__ __forceinline__ float sig_np(float x) {
  return __fdiv_rn(1.0f, __fadd_rn(1.0f, expf(-x)));
}

// Exact ascending-k dot, K=256, single chain — identical FP order to the
// verified baseline. base/strideK4 select original vs transposed layout.
__device__ __forceinline__ float dot256s(const float4* __restrict__ w4,
                                         size_t base, int sK, const float* x) {
  const float4* x4 = (const float4*)x;
  float acc = 0.0f;
  #pragma unroll 8
  for (int i = 0; i < 64; ++i) {
    float4 wv = w4[base + (size_t)i * sK];
    float4 xv = x4[i];
    acc = fmaf(wv.x, xv.x, acc);
    acc = fmaf(wv.y, xv.y, acc);
    acc = fmaf(wv.z, xv.z, acc);
    acc = fmaf(wv.w, xv.w, acc);
  }
  return acc;
}
// Exact ascending plain sum of 256 weights (h = ones case).
__device__ __forceinline__ float sum256s(const float4* __restrict__ w4,
                                         size_t base, int sK) {
  float acc = 0.0f;
  #pragma unroll 8
  for (int i = 0; i < 64; ++i) {
    float4 wv = w4[base + (size_t)i * sK];
    acc = __fadd_rn(acc, wv.x);
    acc = __fadd_rn(acc, wv.y);
    acc = __fadd_rn(acc, wv.z);
    acc = __fadd_rn(acc, wv.w);
  }
  return acc;
}

// ---------------- transpose pre-pass ----------------
struct TransArgs {
  const float* src[9];
  float*       dst[9];
  int          n4[9];      // R*K4 float4 count
  int          rmask[9];   // R-1 (R pow2)
  int          rshift[9];  // log2(R)
  int          K[9];
};

__global__ void transpose_all(TransArgs a) {
  const int gtid = blockIdx.x * blockDim.x + threadIdx.x;
  const int gsz  = gridDim.x * blockDim.x;
  for (int m = 0; m < 9; ++m) {
    const float* __restrict__ src = a.src[m];
    float4* __restrict__ dst = (float4*)a.dst[m];
    const int n = a.n4[m], rm = a.rmask[m], rs = a.rshift[m], K = a.K[m];
    for (int i = gtid; i < n; i += gsz) {
      const int r = i & rm, k4 = i >> rs;
      const float* s = src + (size_t)r * K + (size_t)k4 * 4;
      float4 v; v.x = s[0]; v.y = s[1]; v.z = s[2]; v.w = s[3];
      dst[i] = v;
    }
  }
}

// One WG of 16 waves per CU; thread-per-row ascending chains (exact numerics),
// coalesced via transposed weights when useT=1.
__global__ __launch_bounds__(WGSZ, 4) void planner_kernel(
    const float* __restrict__ inp_start, const float* __restrict__ map_pts,
    const float* __restrict__ ela_w1, const float* __restrict__ ela_w2,
    const float* __restrict__ conv_w, const float* __restrict__ elm_w1,
    const float* __restrict__ elm_w2, const float* __restrict__ ebl_w1,
    const float* __restrict__ ebl_w2, const float* __restrict__ lstm_wih,
    const float* __restrict__ lstm_whh, const float* __restrict__ dm_w1,
    const float* __restrict__ dm_w2, const float* __restrict__ dv_w1,
    const float* __restrict__ dv_w2, const float* __restrict__ wsT,
    int useT, float* __restrict__ g_out) {
  const int b   = blockIdx.x;
  const int tid = threadIdx.x;

  __shared__ unsigned s_mask[kGW];
  __shared__ __align__(16) float s_conv[kOO];   // 16KB
  __shared__ __align__(16) float s_cw[800];     // conv weights (raw)
  __shared__ __align__(16) float s_elah[kH], s_elao[kH], s_elmh[kH], s_elmo[kH];
  __shared__ __align__(16) float s_eblh[kH], s_eblo[kH];
  __shared__ __align__(16) float s_h0[kH], s_c0[kH], s_h1[kH], s_c1[kH];
  __shared__ __align__(16) float s_gate[1024];
  __shared__ __align__(16) float s_tmp[512];    // LN: d, d^2
  __shared__ __align__(16) float s_r[kH], s_dmh[kH], s_dvh[kH];
  __shared__ float s_anchor[3], s_cs[2], s_g6[6];
  __shared__ float s_mu, s_den;

  // ---- init ----
  if (tid == 0) {
    float a2 = inp_start[b * 3 + 2];
    s_anchor[0] = inp_start[b * 3 + 0];
    s_anchor[1] = inp_start[b * 3 + 1];
    s_anchor[2] = a2;
    s_cs[0] = (float)cos((double)a2);
    s_cs[1] = (float)sin((double)a2);
  }
  if (tid < 3) {
    g_out[b * 96 + tid] = inp_start[b * 3 + tid];
    g_out[6144 + b * 96 + tid] = 0.01f;
  }
  __syncthreads();

  // ================= 28 sequential steps, all batch-local =================
  for (int k = 0; k < 28; ++k) {
    const int st = k / 7, a = k % 7;
    const bool a0f = (a == 0);

    // ---- phase 1: clear mask, stage raw conv weights, ela hidden (K=3) ----
    for (int w = tid; w < kGW; w += WGSZ) s_mask[w] = 0u;
    for (int w = tid; w < 800; w += WGSZ) s_cw[w] = conv_w[st * 800 + w];
    if (tid < kH) {
      const float* w1r = ela_w1 + (st * kH + tid) * 3;
      float h = fmaf(s_anchor[2], w1r[2],
                fmaf(s_anchor[1], w1r[1], __fmul_rn(s_anchor[0], w1r[0])));
      s_elah[tid] = fmaxf(h, 0.0f);
    }
    __syncthreads();

    // ---- phase 2: OGM scatter ----
    {
      float ax = s_anchor[0], ay = s_anchor[1], cc = s_cs[0], ss = s_cs[1];
      for (int n = tid; n < kN; n += WGSZ) {
        float mx = __fadd_rn(map_pts[n],      -ax);
        float my = __fadd_rn(map_pts[kN + n], -ay);
        float px = fmaf(ss, my, __fmul_rn(cc, mx));
        float py = fmaf(cc, my, -__fmul_rn(ss, mx));
        bool outb = (fabsf(px) > 12.8f) || (fabsf(py) > 12.8f);
        px = outb ? 0.0f : px;
        py = outb ? 0.0f : py;
        int xi = bin_idx(px), yi = bin_idx(py);
        atomicOr(&s_mask[xi * 4 + (yi >> 5)], 1u << (yi & 31));
      }
    }
    __syncthreads();

    // ---- phase 3: conv 5x5/s2, EXACT baseline (o,ci,t) chain order ----
    for (int q = 0; q < 4; ++q) {
      const int p = tid + (q << 10);
      const int oy = p >> 6, ox = p & 63;
      unsigned occ = 0u;
      for (int ky = 0; ky < 5; ++ky) {
        const int y = 2 * oy - 2 + ky;
        if ((unsigned)y >= 128u) continue;
        const unsigned* row = &s_mask[y * 4];
        for (int kx = 0; kx < 5; ++kx) {
          const int x = 2 * ox - 2 + kx;
          if ((unsigned)x >= 128u) continue;
          if ((row[x >> 5] >> (x & 31)) & 1u) occ |= 1u << (ky * 5 + kx);
        }
      }
      float csum = 0.0f;
      if (occ != 0u) {
        for (int o = 0; o < 8; ++o) {
          float acc = 0.0f;
          const float* wo = s_cw + o * 100;
          for (int ci = 0; ci < 4; ++ci) {
            const float* wc = wo + ci * 25;
            #pragma unroll
            for (int t = 0; t < 25; ++t)
              acc = __fadd_rn(acc, ((occ >> t) & 1u) ? wc[t] : 0.0f);
          }
          float th = tanhf(acc);
          csum = (o == 0) ? th : __fadd_rn(csum, th);
        }
      }
      s_conv[p] = csum;
    }
    __syncthreads();

    // ---- phase 4: ela out (waves 0-3) || elm hidden K=4096 (waves 4-7) ----
    if (tid < kH) {
      const float4* w4 = useT ? (const float4*)(wsT + OFF_ELA2)
                              : (const float4*)ela_w2;
      size_t base; int sK;
      if (useT) { base = (size_t)(st * kH + tid); sK = 1024; }
      else      { base = (size_t)(st * kH + tid) * 64; sK = 1; }
      s_elao[tid] = dot256s(w4, base, sK, s_elah);
    } else if (tid < 512) {
      const int r = tid - kH;
      const float4* w4 = useT ? (const float4*)(wsT + OFF_ELM1)
                              : (const float4*)elm_w1;
      size_t base; int sK;
      if (useT) { base = (size_t)(st * kH + r); sK = 1024; }
      else      { base = (size_t)(st * kH + r) * 1024; sK = 1; }
      const float4* x4 = (const float4*)s_conv;
      float acc = 0.0f;
      #pragma unroll 8
      for (int i = 0; i < 1024; ++i) {
        float4 wv = w4[base + (size_t)i * sK];
        float4 xv = x4[i];
        acc = fmaf(wv.x, xv.x, acc);
        acc = fmaf(wv.y, xv.y, acc);
        acc = fmaf(wv.z, xv.z, acc);
        acc = fmaf(wv.w, xv.w, acc);
      }
      s_elmh[r] = fmaxf(acc, 0.0f);
    }
    __syncthreads();

    // ---- phase 5: elm out ----
    if (tid < kH) {
      const float4* w4 = useT ? (const float4*)(wsT + OFF_ELM2)
                              : (const float4*)elm_w2;
      size_t base; int sK;
      if (useT) { base = (size_t)(st * kH + tid); sK = 1024; }
      else      { base = (size_t)(st * kH + tid) * 64; sK = 1; }
      s_elmo[tid] = dot256s(w4, base, sK, s_elmh);
    }
    __syncthreads();

    // ---- phase 6: ebl hidden (K=512, single ascending chain) ----
    if (tid < kH) {
      const float4* w4 = useT ? (const float4*)(wsT + OFF_EBL1)
                              : (const float4*)ebl_w1;
      size_t base; int sK;
      if (useT) { base = (size_t)(st * kH + tid); sK = 1024; }
      else      { base = (size_t)(st * kH + tid) * 128; sK = 1; }
      const float4* xa = (const float4*)s_elao;
      const float4* xm = (const float4*)s_elmo;
      float acc = 0.0f;
      #pragma unroll 8
      for (int i = 0; i < 64; ++i) {
        float4 wv = w4[base + (size_t)i * sK];
        float4 xv = xa[i];
        acc = fmaf(wv.x, xv.x, acc); acc = fmaf(wv.y, xv.y, acc);
        acc = fmaf(wv.z, xv.z, acc); acc = fmaf(wv.w, xv.w, acc);
      }
      #pragma unroll 8
      for (int i = 0; i < 64; ++i) {
        float4 wv = w4[base + (size_t)(64 + i) * sK];
        float4 xv = xm[i];
        acc = fmaf(wv.x, xv.x, acc); acc = fmaf(wv.y, xv.y, acc);
        acc = fmaf(wv.z, xv.z, acc); acc = fmaf(wv.w, xv.w, acc);
      }
      s_eblh[tid] = fmaxf(acc, 0.0f);
    }
    __syncthreads();

    // ---- phase 7: ebl out ----
    if (tid < kH) {
      const float4* w4 = useT ? (const float4*)(wsT + OFF_EBL2)
                              : (const float4*)ebl_w2;
      size_t base; int sK;
      if (useT) { base = (size_t)(st * kH + tid); sK = 1024; }
      else      { base = (size_t)(st * kH + tid) * 64; sK = 1; }
      s_eblo[tid] = dot256s(w4, base, sK, s_eblh);
    }
    __syncthreads();

    // ---- LSTM layers: 1024 gate rows across all 16 waves ----
    for (int l = 0; l < 2; ++l) {
      {
        const float* xe = (l == 0) ? s_eblo : s_h0;
        const float* xh = (l == 0) ? s_h0 : s_h1;
        const size_t rgl = (size_t)((st * 2 + l) * 1024 + tid);
        const float4 *wi4, *wh4; size_t bi; int sK;
        if (useT) {
          wi4 = (const float4*)(wsT + OFF_WIH);
          wh4 = (const float4*)(wsT + OFF_WHH);
          bi = rgl; sK = 8192;
        } else {
          wi4 = (const float4*)lstm_wih;
          wh4 = (const float4*)lstm_whh;
          bi = rgl * 64; sK = 1;
        }
        float A = dot256s(wi4, bi, sK, xe);
        float Bv = a0f ? sum256s(wh4, bi, sK) : dot256s(wh4, bi, sK, xh);
        s_gate[tid] = __fadd_rn(A, Bv);
      }
      __syncthreads();
      if (tid < kH) {
        float gi = s_gate[tid], gf = s_gate[256 + tid];
        float gg = s_gate[512 + tid], go = s_gate[768 + tid];
        float* sc = (l == 0) ? s_c0 : s_c1;
        float* sh = (l == 0) ? s_h0 : s_h1;
        float cprev = a0f ? 1.0f : sc[tid];
        float cl = __fadd_rn(__fmul_rn(sig_np(gf), cprev),
                             __fmul_rn(sig_np(gi), tanhf(gg)));
        float hl = __fmul_rn(sig_np(go), tanhf(cl));
        sc[tid] = cl; sh[tid] = hl;
      }
      __syncthreads();
    }

    // ---- LayerNorm (numpy pairwise) + r ----
    if (tid == 0) s_mu = __fdiv_rn(np_sum256(s_h1), 256.0f);
    __syncthreads();
    if (tid < kH) {
      float d = __fadd_rn(s_h1[tid], -s_mu);
      s_tmp[tid] = d;
      s_tmp[256 + tid] = __fmul_rn(d, d);
    }
    __syncthreads();
    if (tid == 0) {
      float v = __fdiv_rn(np_sum256(s_tmp + 256), 256.0f);
      s_den = __fsqrt_rn(__fadd_rn(v, 1e-5f));
    }
    __syncthreads();
    if (tid < kH) {
      float r = __fadd_rn(__fdiv_rn(s_tmp[tid], s_den), s_eblo[tid]);
      s_r[tid] = fmaxf(r, 0.0f);
    }
    __syncthreads();

    // ---- dm/dv hidden: 512 rows across 512 threads ----
    if (tid < 512) {
      const int r = tid & 255;
      const bool isv = tid >= kH;
      const float4* w4;
      size_t base; int sK;
      if (useT) {
        w4 = (const float4*)(wsT + (isv ? OFF_DV1 : OFF_DM1));
        base = (size_t)(st * kH + r); sK = 1024;
      } else {
        w4 = (const float4*)(isv ? dv_w1 : dm_w1);
        base = (size_t)(st * kH + r) * 64; sK = 1;
      }
      float v = dot256s(w4, base, sK, s_r);
      (isv ? s_dvh : s_dmh)[r] = fmaxf(v, 0.0f);
    }
    __syncthreads();

    // ---- heads (tiny; original layout, exact ascending) ----
    if (tid < 6) {
      const int d = tid % 3; const bool isv = tid >= 3;
      const float* W = (isv ? dv_w2 : dm_w2) + (st * 3 + d) * kH;
      s_g6[tid] = dot256s((const float4*)W, 0, 1, isv ? s_dvh : s_dmh);
    }
    __syncthreads();

    // ---- anchor update + outputs ----
    if (tid == 0) {
      const float dlmf[3] = {2.0f, 2.0f, 0.5f};
      for (int d = 0; d < 3; ++d) {
        float avn = __fadd_rn(s_anchor[d], __fmul_rn(tanhf(s_g6[d]), dlmf[d]));
        float vvn = __fmul_rn(sig_np(s_g6[3 + d]), 0.1f);
        s_anchor[d] = avn;
        int o = ((b * 4 + st) * 8 + (a + 1)) * 3 + d;
        g_out[o] = avn;
        g_out[6144 + o] = vvn;
        if (a == 6 && st < 3) {
          int o2 = ((b * 4 + st + 1) * 8 + 0) * 3 + d;
          g_out[o2] = avn;
          g_out[6144 + o2] = vvn;
        }
      }
      s_cs[0] = (float)cos((double)s_anchor[2]);
      s_cs[1] = (float)sin((double)s_anchor[2]);
    }
    __syncthreads();
  }
}

extern "C" void kernel_launch(void* const* d_in, const int* in_sizes, int n_in,
                              void* d_out, int out_size, void* d_ws, size_t ws_size,
                              hipStream_t stream) {
  (void)in_sizes; (void)n_in; (void)out_size;
  const int useT = (d_ws != nullptr && ws_size >= WS_FLOATS * sizeof(float)) ? 1 : 0;
  float* wsf = (float*)d_ws;

  if (useT) {
    TransArgs ta;
    const float* srcs[9] = {
        (const float*)d_in[3],  // ela_w2
        (const float*)d_in[5],  // elm_w1
        (const float*)d_in[6],  // elm_w2
        (const float*)d_in[7],  // ebl_w1
        (const float*)d_in[8],  // ebl_w2
        (const float*)d_in[11], // dm_w1
        (const float*)d_in[13], // dv_w1
        (const float*)d_in[9],  // lstm_wih
        (const float*)d_in[10]  // lstm_whh
    };
    float* dsts[9] = {
        wsf + OFF_ELA2, wsf + OFF_ELM1, wsf + OFF_ELM2, wsf + OFF_EBL1,
        wsf + OFF_EBL2, wsf + OFF_DM1,  wsf + OFF_DV1,  wsf + OFF_WIH,
        wsf + OFF_WHH
    };
    const int n4s[9]   = {65536, 1048576, 65536, 131072, 65536, 65536, 65536,
                          524288, 524288};
    const int rms[9]   = {1023, 1023, 1023, 1023, 1023, 1023, 1023, 8191, 8191};
    const int rss[9]   = {10, 10, 10, 10, 10, 10, 10, 13, 13};
    const int Ks[9]    = {256, 4096, 256, 512, 256, 256, 256, 256, 256};
    for (int m = 0; m < 9; ++m) {
      ta.src[m] = srcs[m]; ta.dst[m] = dsts[m]; ta.n4[m] = n4s[m];
      ta.rmask[m] = rms[m]; ta.rshift[m] = rss[m]; ta.K[m] = Ks[m];
    }
    transpose_all<<<dim3(1024), dim3(256), 0, stream>>>(ta);
  }

  planner_kernel<<<dim3(NWG), dim3(WGSZ), 0, stream>>>(
      (const float*)d_in[0],  (const float*)d_in[1],  (const float*)d_in[2],
      (const float*)d_in[3],  (const float*)d_in[4],  (const float*)d_in[5],
      (const float*)d_in[6],  (const float*)d_in[7],  (const float*)d_in[8],
      (const float*)d_in[9],  (const float*)d_in[10], (const float*)d_in[11],
      (const float*)d_in[12], (const float*)d_in[13], (const float*)d_in[14],
      (const float*)wsf, useT, (float*)d_out);
}